// Round 12
// baseline (639.957 us; speedup 1.0000x reference)
//
#include <hip/hip_runtime.h>
#include <hip/hip_bf16.h>

typedef unsigned short u16;
typedef __attribute__((ext_vector_type(8))) __bf16 bf16x8;
typedef __attribute__((ext_vector_type(4))) float f32x4;
typedef __attribute__((ext_vector_type(8))) unsigned short ushort8;

#define GM 8192
#define GN 4096
#define GK 4096
#define NT (GK / 64)  // 64 K-tiles of BK=64

__device__ __forceinline__ u16 f2bf(float f) {
  unsigned u = __float_as_uint(f);
  u += 0x7fffu + ((u >> 16) & 1u);
  return (u16)(u >> 16);
}

// ---- kernel 1: W_eff = bf16(W + 2 * (B @ A))   [4096][4096]
__global__ void build_weff(const float* __restrict__ W,
                           const float* __restrict__ lA,
                           const float* __restrict__ lB,
                           u16* __restrict__ Weff) {
  const int o = blockIdx.x;
  float b[8];
#pragma unroll
  for (int r = 0; r < 8; ++r) b[r] = 2.0f * lB[o * 8 + r];
  const float* wrow = W + (size_t)o * GK;
  u16* orow = Weff + (size_t)o * GK;
  for (int d = threadIdx.x * 4; d < GK; d += blockDim.x * 4) {
    float4 w = *reinterpret_cast<const float4*>(wrow + d);
    float a0 = w.x, a1 = w.y, a2 = w.z, a3 = w.w;
#pragma unroll
    for (int r = 0; r < 8; ++r) {
      float4 a = *reinterpret_cast<const float4*>(lA + r * GK + d);
      a0 += b[r] * a.x; a1 += b[r] * a.y; a2 += b[r] * a.z; a3 += b[r] * a.w;
    }
    ushort4 p;
    p.x = f2bf(a0); p.y = f2bf(a1); p.z = f2bf(a2); p.w = f2bf(a3);
    *reinterpret_cast<ushort4*>(orow + d) = p;
  }
}

// ---- kernel 2: 256x256-tile GEMM, C[m][n] = sum_k x[m][k]*Weff[n][k]
// R12: cvt_bf16 pre-pass FUSED into A-staging. A is loaded f32 from x
// (global_load_dwordx4 -> VGPR), converted RNE in-register
// (__float22bfloat162_rn == standalone pass bit-for-bit), ds_write_b128
// into the swizzled LDS slot (per-lane write addressing -> swizzle applied
// directly; no inverse-source trick). B keeps global_load_lds staging.
// cvt+writes placed between MFMA Q1 and Q2: VALU/LDS-write hides under the
// MFMA stream (separate pipes); vmcnt(0) mid-tile retires A-loads (~1300cy
// old) and B-gloads. lgkmcnt(0)+BAR at tile end publishes the writes.
// Schedule otherwise = R7 free-flow (best known): 1 barrier/tile, 1-deep
// staging, all 24 ds_read_b128 first. 3-bit swizzle (0 conflicts), XCD swz.
__device__ __forceinline__ void gload16(const u16* g, u16* l) {
  __builtin_amdgcn_global_load_lds(
      (const __attribute__((address_space(1))) void*)g,
      (__attribute__((address_space(3))) void*)l, 16, 0, 0);
}

#define BAR()                                  \
  do {                                         \
    asm volatile("" ::: "memory");             \
    __builtin_amdgcn_s_barrier();              \
    asm volatile("" ::: "memory");             \
  } while (0)

__global__ __launch_bounds__(512, 2) void gemm256(const float* __restrict__ X,
                                                  const u16* __restrict__ Bb,
                                                  float* __restrict__ C) {
  // [buf][0=A,1=B][row*64 + k], 2*2*16384*2B = 128 KiB
  __shared__ u16 lds[2][2][256 * 64];

  const int tid = threadIdx.x;
  const int wv = tid >> 6;
  const int l = tid & 63;

  // XCD-aware swizzle: 512 blocks, 512 % 8 == 0 -> simple bijective form
  const int nwg = gridDim.x;
  const int cpx = nwg >> 3;
  const int wg = ((int)blockIdx.x & 7) * cpx + ((int)blockIdx.x >> 3);
  const int tm = wg >> 4;   // GN/256 = 16 tiles in N
  const int tn = wg & 15;

  const int wr = wv >> 2;   // 0..1  (M split)
  const int wc = wv & 3;    // 0..3  (N split)

  // --- staging constants ---
  const int srow = (wv << 3) + (l >> 3);
  const int srl = ((wv & 1) << 3) | (l >> 3);          // B row bits 0..3
  const int skel = ((l & 7) << 3) ^ ((srl & 0xE) << 2);
  const float* xG = X + (size_t)(tm * 256) * GK;       // A source, f32
  const u16* bG = Bb + (size_t)(tn * 256) * GK;

  // --- reader constants ---
  const int frow = l & 15;
  const int fksw = ((l >> 4) << 3) ^ ((frow & 0xE) << 2);
  const int arow = wr * 128 + frow;
  const int brow = wc * 64 + frow;

  // B stage half: r = 0,1 (2 x gload16/wave, pre-swizzled source)
  auto STAGE_B = [&](int th, int r) {
    const int tc = th < NT ? th : NT - 1;
    const int k0 = tc << 6;
    const u16* src = bG + (size_t)(r * 128 + srow) * GK + k0 + skel;
    u16* dst = &lds[th & 1][1][r * 8192 + wv * 512];
#pragma unroll
    for (int j = 0; j < 2; ++j)
      gload16(src + (size_t)(j * 64) * GK, dst + j * 4096);
  };

  // A reg-staging: 8 x dwordx4 f32 loads (lane covers 4 rows x 8 elems)
  const int acol = (l & 7) * 8;  // logical k offset within BK (8 f32)
  auto STAGE_A_LOAD = [&](int th, float4* v) {
    const int tc = th < NT ? th : NT - 1;
    const int k0 = tc << 6;
#pragma unroll
    for (int p = 0; p < 4; ++p) {  // p = r*2+j : row = p*64 + srow
      const float* src = xG + (size_t)(p * 64 + srow) * GK + k0 + acol;
      v[p * 2 + 0] = *reinterpret_cast<const float4*>(src);
      v[p * 2 + 1] = *reinterpret_cast<const float4*>(src + 4);
    }
  };
  auto STAGE_A_WRITE = [&](int th, const float4* v) {
#pragma unroll
    for (int p = 0; p < 4; ++p) {
      const int row = p * 64 + srow;
      u16* dst = &lds[th & 1][0][row * 64 + (acol ^ ((row & 0xE) << 2))];
      const float4 v0 = v[p * 2 + 0], v1 = v[p * 2 + 1];
      __hip_bfloat162 q0 = __float22bfloat162_rn(make_float2(v0.x, v0.y));
      __hip_bfloat162 q1 = __float22bfloat162_rn(make_float2(v0.z, v0.w));
      __hip_bfloat162 q2 = __float22bfloat162_rn(make_float2(v1.x, v1.y));
      __hip_bfloat162 q3 = __float22bfloat162_rn(make_float2(v1.z, v1.w));
      uint4 pk;
      pk.x = *reinterpret_cast<const unsigned*>(&q0);
      pk.y = *reinterpret_cast<const unsigned*>(&q1);
      pk.z = *reinterpret_cast<const unsigned*>(&q2);
      pk.w = *reinterpret_cast<const unsigned*>(&q3);
      *reinterpret_cast<uint4*>(dst) = pk;
    }
  };

  // prologue: stage tile 0 (B via gload_lds, A via reg+cvt)
  {
    STAGE_B(0, 0); STAGE_B(0, 1);
    float4 av[8];
    STAGE_A_LOAD(0, av);
    asm volatile("s_waitcnt vmcnt(0)" ::: "memory");
    STAGE_A_WRITE(0, av);
    asm volatile("s_waitcnt lgkmcnt(0)" ::: "memory");
    BAR();
  }

  f32x4 acc[8][4] = {};
  bf16x8 af_lo[4][2], af_hi[4][2], bfr0[2][2], bfr1[2][2];

  for (int t = 0; t < NT; ++t) {
    const u16* A = &lds[t & 1][0][0];
    const u16* B = &lds[t & 1][1][0];

    // ---- ALL 24 ds_read_b128, consumption order ----
#pragma unroll
    for (int n = 0; n < 2; ++n)
#pragma unroll
      for (int s = 0; s < 2; ++s)
        bfr0[n][s] = *reinterpret_cast<const bf16x8*>(
            B + (brow + n * 16) * 64 + (fksw ^ (s << 5)));
#pragma unroll
    for (int m = 0; m < 4; ++m)
#pragma unroll
      for (int s = 0; s < 2; ++s)
        af_lo[m][s] = *reinterpret_cast<const bf16x8*>(
            A + (arow + m * 16) * 64 + (fksw ^ (s << 5)));
#pragma unroll
    for (int n = 0; n < 2; ++n)
#pragma unroll
      for (int s = 0; s < 2; ++s)
        bfr1[n][s] = *reinterpret_cast<const bf16x8*>(
            B + (brow + (n + 2) * 16) * 64 + (fksw ^ (s << 5)));
#pragma unroll
    for (int m = 0; m < 4; ++m)
#pragma unroll
      for (int s = 0; s < 2; ++s)
        af_hi[m][s] = *reinterpret_cast<const bf16x8*>(
            A + (arow + (m + 4) * 16) * 64 + (fksw ^ (s << 5)));

    // issue next tile's staging loads (B -> LDS DMA, A -> VGPR)
    STAGE_B(t + 1, 0); STAGE_B(t + 1, 1);
    float4 av[8];
    STAGE_A_LOAD(t + 1, av);

    // ---- MFMA Q0, Q1 ----
    __builtin_amdgcn_s_setprio(1);
#pragma unroll
    for (int m = 0; m < 4; ++m)
#pragma unroll
      for (int n = 0; n < 2; ++n)
#pragma unroll
        for (int s = 0; s < 2; ++s)
          acc[m][n] = __builtin_amdgcn_mfma_f32_16x16x32_bf16(
              af_lo[m][s], bfr0[n][s], acc[m][n], 0, 0, 0);
#pragma unroll
    for (int m = 0; m < 4; ++m)
#pragma unroll
      for (int n = 0; n < 2; ++n)
#pragma unroll
        for (int s = 0; s < 2; ++s)
          acc[m][n + 2] = __builtin_amdgcn_mfma_f32_16x16x32_bf16(
              af_lo[m][s], bfr1[n][s], acc[m][n + 2], 0, 0, 0);
    __builtin_amdgcn_s_setprio(0);

    // ---- mid-tile: retire loads, cvt+write A(t+1) (hides under MFMA) ----
    asm volatile("s_waitcnt vmcnt(0)" ::: "memory");
    STAGE_A_WRITE(t + 1, av);

    // ---- MFMA Q2, Q3 ----
    __builtin_amdgcn_s_setprio(1);
#pragma unroll
    for (int m = 0; m < 4; ++m)
#pragma unroll
      for (int n = 0; n < 2; ++n)
#pragma unroll
        for (int s = 0; s < 2; ++s)
          acc[m + 4][n + 2] = __builtin_amdgcn_mfma_f32_16x16x32_bf16(
              af_hi[m][s], bfr1[n][s], acc[m + 4][n + 2], 0, 0, 0);
#pragma unroll
    for (int m = 0; m < 4; ++m)
#pragma unroll
      for (int n = 0; n < 2; ++n)
#pragma unroll
        for (int s = 0; s < 2; ++s)
          acc[m + 4][n] = __builtin_amdgcn_mfma_f32_16x16x32_bf16(
              af_hi[m][s], bfr0[n][s], acc[m + 4][n], 0, 0, 0);
    __builtin_amdgcn_s_setprio(0);

    // tile end: publish A-writes (+ B DMA already vmcnt-retired), flip
    asm volatile("s_waitcnt lgkmcnt(0)" ::: "memory");
    BAR();
  }

  // epilogue: C/D layout col = l&15, row = 4*(l>>4)+j
  const int orow = tm * 256 + wr * 128 + ((l >> 4) << 2);
  const int ocol = tn * 256 + wc * 64 + (l & 15);
#pragma unroll
  for (int m = 0; m < 8; ++m)
#pragma unroll
    for (int n = 0; n < 4; ++n) {
      float* cp = C + (size_t)(orow + m * 16) * GN + (ocol + n * 16);
#pragma unroll
      for (int j = 0; j < 4; ++j) cp[(size_t)j * GN] = acc[m][n][j];
    }
}

extern "C" void kernel_launch(void* const* d_in, const int* in_sizes, int n_in,
                              void* d_out, int out_size, void* d_ws, size_t ws_size,
                              hipStream_t stream) {
  const float* x  = (const float*)d_in[0];
  const float* W  = (const float*)d_in[1];
  const float* lA = (const float*)d_in[2];
  const float* lB = (const float*)d_in[3];
  float* out = (float*)d_out;

  u16* weff = (u16*)d_ws;  // 32 MiB

  build_weff<<<GN, 256, 0, stream>>>(W, lA, lB, weff);
  gemm256<<<(GM / 256) * (GN / 256), 512, 0, stream>>>(x, weff, out);
}

// Round 13
// 395.680 us; speedup vs baseline: 1.6174x; 1.6174x over previous
//
#include <hip/hip_runtime.h>
#include <hip/hip_bf16.h>

typedef unsigned short u16;
typedef __attribute__((ext_vector_type(8))) __bf16 bf16x8;
typedef __attribute__((ext_vector_type(4))) float f32x4;
typedef __attribute__((ext_vector_type(8))) unsigned short ushort8;

#define GM 8192
#define GN 4096
#define GK 4096
#define NT (GK / 64)  // 64 K-tiles of BK=64

__device__ __forceinline__ u16 f2bf(float f) {
  unsigned u = __float_as_uint(f);
  u += 0x7fffu + ((u >> 16) & 1u);
  return (u16)(u >> 16);
}

// ---- kernel 1: W_eff = bf16(W + 2 * (B @ A))   [4096][4096]
__global__ void build_weff(const float* __restrict__ W,
                           const float* __restrict__ lA,
                           const float* __restrict__ lB,
                           u16* __restrict__ Weff) {
  const int o = blockIdx.x;
  float b[8];
#pragma unroll
  for (int r = 0; r < 8; ++r) b[r] = 2.0f * lB[o * 8 + r];
  const float* wrow = W + (size_t)o * GK;
  u16* orow = Weff + (size_t)o * GK;
  for (int d = threadIdx.x * 4; d < GK; d += blockDim.x * 4) {
    float4 w = *reinterpret_cast<const float4*>(wrow + d);
    float a0 = w.x, a1 = w.y, a2 = w.z, a3 = w.w;
#pragma unroll
    for (int r = 0; r < 8; ++r) {
      float4 a = *reinterpret_cast<const float4*>(lA + r * GK + d);
      a0 += b[r] * a.x; a1 += b[r] * a.y; a2 += b[r] * a.z; a3 += b[r] * a.w;
    }
    ushort4 p;
    p.x = f2bf(a0); p.y = f2bf(a1); p.z = f2bf(a2); p.w = f2bf(a3);
    *reinterpret_cast<ushort4*>(orow + d) = p;
  }
}

// ---- kernel 2: 256x256-tile GEMM, C[m][n] = sum_k x[m][k]*Weff[n][k]
// R13: R12's fused A-cvt staging, register-neutral. R12 spilled (284 > 256
// unified regs: av[8]=32 held across Q0/Q1 on top of af 64 + bfr 32 + acc
// 128). Fix: af_hi moves to JIT mid-tile (frees 32), so peak = af_lo 32 +
// bfr 32 + av 32 + addr ~25 = ~121 arch VGPR + 128 acc = 249 < 256.
// Mid-tile order: issue af_hi ds_reads -> vmcnt(0) -> A cvt+ds_write (av
// dies, regs recycle) -> Q2/Q3. Tile-end lgkmcnt(0)+BAR publishes writes.
// A loaded f32 from x, converted RNE in-reg (bit-identical to the old
// standalone cvt pass), ds_write_b128 to swizzled slot (per-lane write
// addressing -> swizzle applied directly). B keeps global_load_lds.
// 1 barrier/tile, 1-deep staging, 3-bit swizzle (0 conflicts), XCD swz.
__device__ __forceinline__ void gload16(const u16* g, u16* l) {
  __builtin_amdgcn_global_load_lds(
      (const __attribute__((address_space(1))) void*)g,
      (__attribute__((address_space(3))) void*)l, 16, 0, 0);
}

#define BAR()                                  \
  do {                                         \
    asm volatile("" ::: "memory");             \
    __builtin_amdgcn_s_barrier();              \
    asm volatile("" ::: "memory");             \
  } while (0)

__global__ __launch_bounds__(512, 2) void gemm256(const float* __restrict__ X,
                                                  const u16* __restrict__ Bb,
                                                  float* __restrict__ C) {
  // [buf][0=A,1=B][row*64 + k], 2*2*16384*2B = 128 KiB
  __shared__ u16 lds[2][2][256 * 64];

  const int tid = threadIdx.x;
  const int wv = tid >> 6;
  const int l = tid & 63;

  // XCD-aware swizzle: 512 blocks, 512 % 8 == 0 -> simple bijective form
  const int nwg = gridDim.x;
  const int cpx = nwg >> 3;
  const int wg = ((int)blockIdx.x & 7) * cpx + ((int)blockIdx.x >> 3);
  const int tm = wg >> 4;   // GN/256 = 16 tiles in N
  const int tn = wg & 15;

  const int wr = wv >> 2;   // 0..1  (M split)
  const int wc = wv & 3;    // 0..3  (N split)

  // --- staging constants ---
  const int srow = (wv << 3) + (l >> 3);
  const int srl = ((wv & 1) << 3) | (l >> 3);          // B row bits 0..3
  const int skel = ((l & 7) << 3) ^ ((srl & 0xE) << 2);
  const float* xG = X + (size_t)(tm * 256) * GK;       // A source, f32
  const u16* bG = Bb + (size_t)(tn * 256) * GK;

  // --- reader constants ---
  const int frow = l & 15;
  const int fksw = ((l >> 4) << 3) ^ ((frow & 0xE) << 2);
  const int arow = wr * 128 + frow;
  const int brow = wc * 64 + frow;

  // B stage half: r = 0,1 (2 x gload16/wave, pre-swizzled source)
  auto STAGE_B = [&](int th, int r) {
    const int tc = th < NT ? th : NT - 1;
    const int k0 = tc << 6;
    const u16* src = bG + (size_t)(r * 128 + srow) * GK + k0 + skel;
    u16* dst = &lds[th & 1][1][r * 8192 + wv * 512];
#pragma unroll
    for (int j = 0; j < 2; ++j)
      gload16(src + (size_t)(j * 64) * GK, dst + j * 4096);
  };

  // A reg-staging: 8 x dwordx4 f32 loads (lane covers 4 rows x 8 elems)
  const int acol = (l & 7) * 8;  // logical k offset within BK (8 f32)
  auto STAGE_A_LOAD = [&](int th, float4* v) {
    const int tc = th < NT ? th : NT - 1;
    const int k0 = tc << 6;
#pragma unroll
    for (int p = 0; p < 4; ++p) {  // row = p*64 + srow
      const float* src = xG + (size_t)(p * 64 + srow) * GK + k0 + acol;
      v[p * 2 + 0] = *reinterpret_cast<const float4*>(src);
      v[p * 2 + 1] = *reinterpret_cast<const float4*>(src + 4);
    }
  };
  auto STAGE_A_WRITE = [&](int th, const float4* v) {
#pragma unroll
    for (int p = 0; p < 4; ++p) {
      const int row = p * 64 + srow;
      u16* dst = &lds[th & 1][0][row * 64 + (acol ^ ((row & 0xE) << 2))];
      const float4 v0 = v[p * 2 + 0], v1 = v[p * 2 + 1];
      __hip_bfloat162 q0 = __float22bfloat162_rn(make_float2(v0.x, v0.y));
      __hip_bfloat162 q1 = __float22bfloat162_rn(make_float2(v0.z, v0.w));
      __hip_bfloat162 q2 = __float22bfloat162_rn(make_float2(v1.x, v1.y));
      __hip_bfloat162 q3 = __float22bfloat162_rn(make_float2(v1.z, v1.w));
      uint4 pk;
      pk.x = *reinterpret_cast<const unsigned*>(&q0);
      pk.y = *reinterpret_cast<const unsigned*>(&q1);
      pk.z = *reinterpret_cast<const unsigned*>(&q2);
      pk.w = *reinterpret_cast<const unsigned*>(&q3);
      *reinterpret_cast<uint4*>(dst) = pk;
    }
  };

  // prologue: stage tile 0 (B via gload_lds, A via reg+cvt)
  {
    STAGE_B(0, 0); STAGE_B(0, 1);
    float4 av[8];
    STAGE_A_LOAD(0, av);
    asm volatile("s_waitcnt vmcnt(0)" ::: "memory");
    STAGE_A_WRITE(0, av);
    asm volatile("s_waitcnt lgkmcnt(0)" ::: "memory");
    BAR();
  }

  f32x4 acc[8][4] = {};
  bf16x8 af_lo[4][2], af_hi[4][2], bfr0[2][2], bfr1[2][2];

  for (int t = 0; t < NT; ++t) {
    const u16* A = &lds[t & 1][0][0];
    const u16* B = &lds[t & 1][1][0];

    // issue next tile's staging loads first (B -> LDS DMA, A -> VGPR)
    STAGE_B(t + 1, 0); STAGE_B(t + 1, 1);
    float4 av[8];
    STAGE_A_LOAD(t + 1, av);

    // ---- 16 ds_read_b128 (bfr0, af_lo, bfr1), consumption order ----
#pragma unroll
    for (int n = 0; n < 2; ++n)
#pragma unroll
      for (int s = 0; s < 2; ++s)
        bfr0[n][s] = *reinterpret_cast<const bf16x8*>(
            B + (brow + n * 16) * 64 + (fksw ^ (s << 5)));
#pragma unroll
    for (int m = 0; m < 4; ++m)
#pragma unroll
      for (int s = 0; s < 2; ++s)
        af_lo[m][s] = *reinterpret_cast<const bf16x8*>(
            A + (arow + m * 16) * 64 + (fksw ^ (s << 5)));
#pragma unroll
    for (int n = 0; n < 2; ++n)
#pragma unroll
      for (int s = 0; s < 2; ++s)
        bfr1[n][s] = *reinterpret_cast<const bf16x8*>(
            B + (brow + (n + 2) * 16) * 64 + (fksw ^ (s << 5)));

    // ---- MFMA Q0, Q1 ----
    __builtin_amdgcn_s_setprio(1);
#pragma unroll
    for (int m = 0; m < 4; ++m)
#pragma unroll
      for (int n = 0; n < 2; ++n)
#pragma unroll
        for (int s = 0; s < 2; ++s)
          acc[m][n] = __builtin_amdgcn_mfma_f32_16x16x32_bf16(
              af_lo[m][s], bfr0[n][s], acc[m][n], 0, 0, 0);
#pragma unroll
    for (int m = 0; m < 4; ++m)
#pragma unroll
      for (int n = 0; n < 2; ++n)
#pragma unroll
        for (int s = 0; s < 2; ++s)
          acc[m][n + 2] = __builtin_amdgcn_mfma_f32_16x16x32_bf16(
              af_lo[m][s], bfr1[n][s], acc[m][n + 2], 0, 0, 0);
    __builtin_amdgcn_s_setprio(0);

    // ---- mid-tile: af_hi JIT reads; retire VMEM; cvt+write A(t+1) ----
#pragma unroll
    for (int m = 0; m < 4; ++m)
#pragma unroll
      for (int s = 0; s < 2; ++s)
        af_hi[m][s] = *reinterpret_cast<const bf16x8*>(
            A + (arow + (m + 4) * 16) * 64 + (fksw ^ (s << 5)));
    asm volatile("s_waitcnt vmcnt(0)" ::: "memory");
    STAGE_A_WRITE(t + 1, av);  // av dies here -> regs recycle for Q2/Q3

    // ---- MFMA Q2, Q3 ----
    __builtin_amdgcn_s_setprio(1);
#pragma unroll
    for (int m = 0; m < 4; ++m)
#pragma unroll
      for (int n = 0; n < 2; ++n)
#pragma unroll
        for (int s = 0; s < 2; ++s)
          acc[m + 4][n + 2] = __builtin_amdgcn_mfma_f32_16x16x32_bf16(
              af_hi[m][s], bfr1[n][s], acc[m + 4][n + 2], 0, 0, 0);
#pragma unroll
    for (int m = 0; m < 4; ++m)
#pragma unroll
      for (int n = 0; n < 2; ++n)
#pragma unroll
        for (int s = 0; s < 2; ++s)
          acc[m + 4][n] = __builtin_amdgcn_mfma_f32_16x16x32_bf16(
              af_hi[m][s], bfr0[n][s], acc[m + 4][n], 0, 0, 0);
    __builtin_amdgcn_s_setprio(0);

    // tile end: publish A-writes (B DMA already vmcnt-retired), flip
    asm volatile("s_waitcnt lgkmcnt(0)" ::: "memory");
    BAR();
  }

  // epilogue: C/D layout col = l&15, row = 4*(l>>4)+j
  const int orow = tm * 256 + wr * 128 + ((l >> 4) << 2);
  const int ocol = tn * 256 + wc * 64 + (l & 15);
#pragma unroll
  for (int m = 0; m < 8; ++m)
#pragma unroll
    for (int n = 0; n < 4; ++n) {
      float* cp = C + (size_t)(orow + m * 16) * GN + (ocol + n * 16);
#pragma unroll
      for (int j = 0; j < 4; ++j) cp[(size_t)j * GN] = acc[m][n][j];
    }
}

extern "C" void kernel_launch(void* const* d_in, const int* in_sizes, int n_in,
                              void* d_out, int out_size, void* d_ws, size_t ws_size,
                              hipStream_t stream) {
  const float* x  = (const float*)d_in[0];
  const float* W  = (const float*)d_in[1];
  const float* lA = (const float*)d_in[2];
  const float* lB = (const float*)d_in[3];
  float* out = (float*)d_out;

  u16* weff = (u16*)d_ws;  // 32 MiB

  build_weff<<<GN, 256, 0, stream>>>(W, lA, lB, weff);
  gemm256<<<(GM / 256) * (GN / 256), 512, 0, stream>>>(x, weff, out);
}

// Round 14
// 345.897 us; speedup vs baseline: 1.8501x; 1.1439x over previous
//
#include <hip/hip_runtime.h>
#include <hip/hip_bf16.h>

typedef unsigned short u16;
typedef __attribute__((ext_vector_type(8))) __bf16 bf16x8;
typedef __attribute__((ext_vector_type(4))) float f32x4;
typedef __attribute__((ext_vector_type(8))) unsigned short ushort8;

#define GM 8192
#define GN 4096
#define GK 4096
#define NT (GK / 64)  // 64 K-tiles of BK=64

__device__ __forceinline__ u16 f2bf(float f) {
  unsigned u = __float_as_uint(f);
  u += 0x7fffu + ((u >> 16) & 1u);
  return (u16)(u >> 16);
}

// ---- kernel 1: W_eff = bf16(W + 2 * (B @ A))   [4096][4096]
__global__ void build_weff(const float* __restrict__ W,
                           const float* __restrict__ lA,
                           const float* __restrict__ lB,
                           u16* __restrict__ Weff) {
  const int o = blockIdx.x;
  float b[8];
#pragma unroll
  for (int r = 0; r < 8; ++r) b[r] = 2.0f * lB[o * 8 + r];
  const float* wrow = W + (size_t)o * GK;
  u16* orow = Weff + (size_t)o * GK;
  for (int d = threadIdx.x * 4; d < GK; d += blockDim.x * 4) {
    float4 w = *reinterpret_cast<const float4*>(wrow + d);
    float a0 = w.x, a1 = w.y, a2 = w.z, a3 = w.w;
#pragma unroll
    for (int r = 0; r < 8; ++r) {
      float4 a = *reinterpret_cast<const float4*>(lA + r * GK + d);
      a0 += b[r] * a.x; a1 += b[r] * a.y; a2 += b[r] * a.z; a3 += b[r] * a.w;
    }
    ushort4 p;
    p.x = f2bf(a0); p.y = f2bf(a1); p.z = f2bf(a2); p.w = f2bf(a3);
    *reinterpret_cast<ushort4*>(orow + d) = p;
  }
}

// ---- kernel 2: 256x256-tile GEMM, C[m][n] = sum_k x[m][k]*Weff[n][k]
// R14: R13 fusion + counted-vmcnt fix. R13's regression (375us, MfmaUtil
// 30%) was over-sync: mid-tile vmcnt(0) retired the B global_load_lds DMA
// of t+1 (no reason to complete until next barrier), stalling all waves.
// Fix: issue A-loads FIRST (8), then B-DMA (4); VMEM retires in order, so
// mid-tile vmcnt(4) retires exactly the A-loads (cover = Q0+Q1+Q2 ~1860cy)
// and leaves B-DMA drifting; tile-end vmcnt(0) retires B (~full tile old,
// free) before lgkmcnt(0)+BAR publishes the A ds_writes.
// Register peak ~244 <= 256 (af_lo and af_hi phases disjoint, av dies at
// the mid-tile write). A: f32 loads + RNE cvt in-reg (bit-identical to the
// old standalone pass) + swizzled ds_write_b128. B: global_load_lds with
// pre-swizzled source. 1 barrier/tile, 3-bit swizzle, XCD swizzle.
__device__ __forceinline__ void gload16(const u16* g, u16* l) {
  __builtin_amdgcn_global_load_lds(
      (const __attribute__((address_space(1))) void*)g,
      (__attribute__((address_space(3))) void*)l, 16, 0, 0);
}

#define BAR()                                  \
  do {                                         \
    asm volatile("" ::: "memory");             \
    __builtin_amdgcn_s_barrier();              \
    asm volatile("" ::: "memory");             \
  } while (0)

__global__ __launch_bounds__(512, 2) void gemm256(const float* __restrict__ X,
                                                  const u16* __restrict__ Bb,
                                                  float* __restrict__ C) {
  // [buf][0=A,1=B][row*64 + k], 2*2*16384*2B = 128 KiB
  __shared__ u16 lds[2][2][256 * 64];

  const int tid = threadIdx.x;
  const int wv = tid >> 6;
  const int l = tid & 63;

  // XCD-aware swizzle: 512 blocks, 512 % 8 == 0 -> simple bijective form
  const int nwg = gridDim.x;
  const int cpx = nwg >> 3;
  const int wg = ((int)blockIdx.x & 7) * cpx + ((int)blockIdx.x >> 3);
  const int tm = wg >> 4;   // GN/256 = 16 tiles in N
  const int tn = wg & 15;

  const int wr = wv >> 2;   // 0..1  (M split)
  const int wc = wv & 3;    // 0..3  (N split)

  // --- staging constants ---
  const int srow = (wv << 3) + (l >> 3);
  const int srl = ((wv & 1) << 3) | (l >> 3);          // B row bits 0..3
  const int skel = ((l & 7) << 3) ^ ((srl & 0xE) << 2);
  const float* xG = X + (size_t)(tm * 256) * GK;       // A source, f32
  const u16* bG = Bb + (size_t)(tn * 256) * GK;

  // --- reader constants ---
  const int frow = l & 15;
  const int fksw = ((l >> 4) << 3) ^ ((frow & 0xE) << 2);
  const int arow = wr * 128 + frow;
  const int brow = wc * 64 + frow;

  // B stage half: r = 0,1 (2 x gload16/wave, pre-swizzled source)
  auto STAGE_B = [&](int th, int r) {
    const int tc = th < NT ? th : NT - 1;
    const int k0 = tc << 6;
    const u16* src = bG + (size_t)(r * 128 + srow) * GK + k0 + skel;
    u16* dst = &lds[th & 1][1][r * 8192 + wv * 512];
#pragma unroll
    for (int j = 0; j < 2; ++j)
      gload16(src + (size_t)(j * 64) * GK, dst + j * 4096);
  };

  // A reg-staging: 8 x dwordx4 f32 loads (lane covers 4 rows x 8 elems)
  const int acol = (l & 7) * 8;  // logical k offset within BK (8 f32)
  auto STAGE_A_LOAD = [&](int th, float4* v) {
    const int tc = th < NT ? th : NT - 1;
    const int k0 = tc << 6;
#pragma unroll
    for (int p = 0; p < 4; ++p) {  // row = p*64 + srow
      const float* src = xG + (size_t)(p * 64 + srow) * GK + k0 + acol;
      v[p * 2 + 0] = *reinterpret_cast<const float4*>(src);
      v[p * 2 + 1] = *reinterpret_cast<const float4*>(src + 4);
    }
  };
  auto STAGE_A_WRITE = [&](int th, const float4* v) {
#pragma unroll
    for (int p = 0; p < 4; ++p) {
      const int row = p * 64 + srow;
      u16* dst = &lds[th & 1][0][row * 64 + (acol ^ ((row & 0xE) << 2))];
      const float4 v0 = v[p * 2 + 0], v1 = v[p * 2 + 1];
      __hip_bfloat162 q0 = __float22bfloat162_rn(make_float2(v0.x, v0.y));
      __hip_bfloat162 q1 = __float22bfloat162_rn(make_float2(v0.z, v0.w));
      __hip_bfloat162 q2 = __float22bfloat162_rn(make_float2(v1.x, v1.y));
      __hip_bfloat162 q3 = __float22bfloat162_rn(make_float2(v1.z, v1.w));
      uint4 pk;
      pk.x = *reinterpret_cast<const unsigned*>(&q0);
      pk.y = *reinterpret_cast<const unsigned*>(&q1);
      pk.z = *reinterpret_cast<const unsigned*>(&q2);
      pk.w = *reinterpret_cast<const unsigned*>(&q3);
      *reinterpret_cast<uint4*>(dst) = pk;
    }
  };

  // prologue: stage tile 0 (A via reg+cvt, B via gload_lds)
  {
    float4 av[8];
    STAGE_A_LOAD(0, av);
    STAGE_B(0, 0); STAGE_B(0, 1);
    asm volatile("s_waitcnt vmcnt(0)" ::: "memory");
    STAGE_A_WRITE(0, av);
    asm volatile("s_waitcnt lgkmcnt(0)" ::: "memory");
    BAR();
  }

  f32x4 acc[8][4] = {};
  bf16x8 af_lo[4][2], af_hi[4][2], bfr0[2][2], bfr1[2][2];

  for (int t = 0; t < NT; ++t) {
    const u16* A = &lds[t & 1][0][0];
    const u16* B = &lds[t & 1][1][0];

    // issue t+1 staging: A-loads FIRST (8), then B-DMA (4) — in-order
    // retirement makes mid-tile vmcnt(4) == "A retired, B drifting".
    float4 av[8];
    STAGE_A_LOAD(t + 1, av);
    STAGE_B(t + 1, 0); STAGE_B(t + 1, 1);

    // ---- 16 ds_read_b128 (bfr0, af_lo, bfr1), consumption order ----
#pragma unroll
    for (int n = 0; n < 2; ++n)
#pragma unroll
      for (int s = 0; s < 2; ++s)
        bfr0[n][s] = *reinterpret_cast<const bf16x8*>(
            B + (brow + n * 16) * 64 + (fksw ^ (s << 5)));
#pragma unroll
    for (int m = 0; m < 4; ++m)
#pragma unroll
      for (int s = 0; s < 2; ++s)
        af_lo[m][s] = *reinterpret_cast<const bf16x8*>(
            A + (arow + m * 16) * 64 + (fksw ^ (s << 5)));
#pragma unroll
    for (int n = 0; n < 2; ++n)
#pragma unroll
      for (int s = 0; s < 2; ++s)
        bfr1[n][s] = *reinterpret_cast<const bf16x8*>(
            B + (brow + (n + 2) * 16) * 64 + (fksw ^ (s << 5)));

    // ---- MFMA Q0, Q1 ----
    __builtin_amdgcn_s_setprio(1);
#pragma unroll
    for (int m = 0; m < 4; ++m)
#pragma unroll
      for (int n = 0; n < 2; ++n)
#pragma unroll
        for (int s = 0; s < 2; ++s)
          acc[m][n] = __builtin_amdgcn_mfma_f32_16x16x32_bf16(
              af_lo[m][s], bfr0[n][s], acc[m][n], 0, 0, 0);
#pragma unroll
    for (int m = 0; m < 4; ++m)
#pragma unroll
      for (int n = 0; n < 2; ++n)
#pragma unroll
        for (int s = 0; s < 2; ++s)
          acc[m][n + 2] = __builtin_amdgcn_mfma_f32_16x16x32_bf16(
              af_lo[m][s], bfr1[n][s], acc[m][n + 2], 0, 0, 0);
    __builtin_amdgcn_s_setprio(0);

    // ---- af_hi JIT reads, then Q2 ----
#pragma unroll
    for (int m = 0; m < 4; ++m)
#pragma unroll
      for (int s = 0; s < 2; ++s)
        af_hi[m][s] = *reinterpret_cast<const bf16x8*>(
            A + (arow + (m + 4) * 16) * 64 + (fksw ^ (s << 5)));
    __builtin_amdgcn_s_setprio(1);
#pragma unroll
    for (int m = 0; m < 4; ++m)
#pragma unroll
      for (int n = 0; n < 2; ++n)
#pragma unroll
        for (int s = 0; s < 2; ++s)
          acc[m + 4][n + 2] = __builtin_amdgcn_mfma_f32_16x16x32_bf16(
              af_hi[m][s], bfr1[n][s], acc[m + 4][n + 2], 0, 0, 0);
    __builtin_amdgcn_s_setprio(0);

    // ---- retire A-loads only (B-DMA keeps drifting); cvt+write A(t+1) ----
    asm volatile("s_waitcnt vmcnt(4)" ::: "memory");
    STAGE_A_WRITE(t + 1, av);  // av dies -> regs recycle for Q3

    // ---- MFMA Q3 ----
    __builtin_amdgcn_s_setprio(1);
#pragma unroll
    for (int m = 0; m < 4; ++m)
#pragma unroll
      for (int n = 0; n < 2; ++n)
#pragma unroll
        for (int s = 0; s < 2; ++s)
          acc[m + 4][n] = __builtin_amdgcn_mfma_f32_16x16x32_bf16(
              af_hi[m][s], bfr0[n][s], acc[m + 4][n], 0, 0, 0);
    __builtin_amdgcn_s_setprio(0);

    // tile end: retire B-DMA (full tile old), publish A-writes, flip
    asm volatile("s_waitcnt vmcnt(0) lgkmcnt(0)" ::: "memory");
    BAR();
  }

  // epilogue: C/D layout col = l&15, row = 4*(l>>4)+j
  const int orow = tm * 256 + wr * 128 + ((l >> 4) << 2);
  const int ocol = tn * 256 + wc * 64 + (l & 15);
#pragma unroll
  for (int m = 0; m < 8; ++m)
#pragma unroll
    for (int n = 0; n < 4; ++n) {
      float* cp = C + (size_t)(orow + m * 16) * GN + (ocol + n * 16);
#pragma unroll
      for (int j = 0; j < 4; ++j) cp[(size_t)j * GN] = acc[m][n][j];
    }
}

extern "C" void kernel_launch(void* const* d_in, const int* in_sizes, int n_in,
                              void* d_out, int out_size, void* d_ws, size_t ws_size,
                              hipStream_t stream) {
  const float* x  = (const float*)d_in[0];
  const float* W  = (const float*)d_in[1];
  const float* lA = (const float*)d_in[2];
  const float* lB = (const float*)d_in[3];
  float* out = (float*)d_out;

  u16* weff = (u16*)d_ws;  // 32 MiB

  build_weff<<<GN, 256, 0, stream>>>(W, lA, lB, weff);
  gemm256<<<(GM / 256) * (GN / 256), 512, 0, stream>>>(x, weff, out);
}

// Round 15
// 286.645 us; speedup vs baseline: 2.2326x; 1.2067x over previous
//
#include <hip/hip_runtime.h>
#include <hip/hip_bf16.h>

typedef unsigned short u16;
typedef __attribute__((ext_vector_type(8))) __bf16 bf16x8;
typedef __attribute__((ext_vector_type(4))) float f32x4;
typedef __attribute__((ext_vector_type(8))) unsigned short ushort8;

#define GM 8192
#define GN 4096
#define GK 4096
#define NT (GK / 64)  // 64 K-tiles of BK=64

__device__ __forceinline__ u16 f2bf(float f) {
  unsigned u = __float_as_uint(f);
  u += 0x7fffu + ((u >> 16) & 1u);
  return (u16)(u >> 16);
}

// ---- kernel 1: fused pre-pass.
// blocks [0, GN):        Weff[o][:] = bf16(W[o][:] + 2 * (B@A)[o][:])
// blocks [GN, GN+8192):  xb = bf16(x), 16 elems/thread (4096 elems/block)
// Both jobs are memory-bound; one launch lets them share the device and
// saves a launch gap vs two kernels.
__global__ void prep(const float* __restrict__ W,
                     const float* __restrict__ lA,
                     const float* __restrict__ lB,
                     u16* __restrict__ Weff,
                     const float* __restrict__ x,
                     u16* __restrict__ xb) {
  const int bid = blockIdx.x;
  if (bid < GN) {
    const int o = bid;
    float b[8];
#pragma unroll
    for (int r = 0; r < 8; ++r) b[r] = 2.0f * lB[o * 8 + r];
    const float* wrow = W + (size_t)o * GK;
    u16* orow = Weff + (size_t)o * GK;
    for (int d = threadIdx.x * 4; d < GK; d += blockDim.x * 4) {
      float4 w = *reinterpret_cast<const float4*>(wrow + d);
      float a0 = w.x, a1 = w.y, a2 = w.z, a3 = w.w;
#pragma unroll
      for (int r = 0; r < 8; ++r) {
        float4 a = *reinterpret_cast<const float4*>(lA + r * GK + d);
        a0 += b[r] * a.x; a1 += b[r] * a.y; a2 += b[r] * a.z; a3 += b[r] * a.w;
      }
      ushort4 p;
      p.x = f2bf(a0); p.y = f2bf(a1); p.z = f2bf(a2); p.w = f2bf(a3);
      *reinterpret_cast<ushort4*>(orow + d) = p;
    }
  } else {
    // cvt: 16 f32 -> bf16 per thread
    const size_t base =
        ((size_t)(bid - GN) * 256 + threadIdx.x) * 16;
#pragma unroll
    for (int h = 0; h < 2; ++h) {
      const size_t i = base + h * 8;
      float4 v0 = *reinterpret_cast<const float4*>(x + i);
      float4 v1 = *reinterpret_cast<const float4*>(x + i + 4);
      ushort8 o;
      o[0] = f2bf(v0.x); o[1] = f2bf(v0.y); o[2] = f2bf(v0.z); o[3] = f2bf(v0.w);
      o[4] = f2bf(v1.x); o[5] = f2bf(v1.y); o[6] = f2bf(v1.z); o[7] = f2bf(v1.w);
      *reinterpret_cast<ushort8*>(xb + i) = o;
    }
  }
}

// ---- kernel 2: 256x256-tile GEMM, C[m][n] = sum_k A[m][k]*B[n][k]
// R15 = R11 verbatim (measured best: 230us, MfmaUtil 54.5%, 0 conflicts).
// R7/R9/R11 free-flow family: 1 barrier + vmcnt(0) per tile, 1-deep
// staging, all 24 ds_read_b128 first, MFMA quadrant stream, T19 SGB
// emission script, 3-bit LDS swizzle, XCD swizzle, setprio around MFMA.
// Fusion of the cvt into A-staging was tried (R12-R14) and loses: with
// 128KiB LDS there is exactly 1 block/CU, so every extra mandatory wait
// lands on the whole CU's critical path (no co-resident block slack).
__device__ __forceinline__ void gload16(const u16* g, u16* l) {
  __builtin_amdgcn_global_load_lds(
      (const __attribute__((address_space(1))) void*)g,
      (__attribute__((address_space(3))) void*)l, 16, 0, 0);
}

#define BAR()                                  \
  do {                                         \
    asm volatile("" ::: "memory");             \
    __builtin_amdgcn_s_barrier();              \
    asm volatile("" ::: "memory");             \
  } while (0)

#define SGB __builtin_amdgcn_sched_group_barrier

__global__ __launch_bounds__(512, 2) void gemm256(const u16* __restrict__ Ab,
                                                  const u16* __restrict__ Bb,
                                                  float* __restrict__ C) {
  // [buf][0=A,1=B][row*64 + k], 2*2*16384*2B = 128 KiB
  __shared__ u16 lds[2][2][256 * 64];

  const int tid = threadIdx.x;
  const int wv = tid >> 6;
  const int l = tid & 63;

  // XCD-aware swizzle: 512 blocks, 512 % 8 == 0 -> simple bijective form
  const int nwg = gridDim.x;
  const int cpx = nwg >> 3;
  const int wg = ((int)blockIdx.x & 7) * cpx + ((int)blockIdx.x >> 3);
  const int tm = wg >> 4;   // GN/256 = 16 tiles in N
  const int tn = wg & 15;

  const int wr = wv >> 2;   // 0..1  (M split)
  const int wc = wv & 3;    // 0..3  (N split)

  // --- staging constants ---
  const int srow = (wv << 3) + (l >> 3);
  const int srl = ((wv & 1) << 3) | (l >> 3);          // row bits 0..3
  const int skel = ((l & 7) << 3) ^ ((srl & 0xE) << 2);
  const u16* aG = Ab + (size_t)(tm * 256) * GK;
  const u16* bG = Bb + (size_t)(tn * 256) * GK;

  // --- reader constants ---
  const int frow = l & 15;
  const int fksw = ((l >> 4) << 3) ^ ((frow & 0xE) << 2);
  const int arow = wr * 128 + frow;
  const int brow = wc * 64 + frow;

  // stage half-tile: th = K-tile (clamped), r: 0=A0,1=A1,2=B0,3=B1
  auto STAGE = [&](int th, int r) {
    const int tc = th < NT ? th : NT - 1;  // clamp (tail garbage never read)
    const int k0 = tc << 6;
    const u16* src = (r < 2 ? aG : bG) +
                     (size_t)((r & 1) * 128 + srow) * GK + k0 + skel;
    u16* dst = &lds[th & 1][r >> 1][(r & 1) * 8192 + wv * 512];
#pragma unroll
    for (int j = 0; j < 2; ++j)
      gload16(src + (size_t)(j * 64) * GK, dst + j * 4096);
  };

  // prologue: stage tile 0 only (1-deep pipeline)
  STAGE(0, 0); STAGE(0, 1); STAGE(0, 2); STAGE(0, 3);

  f32x4 acc[8][4] = {};
  bf16x8 af_lo[4][2], af_hi[4][2], bfr0[2][2], bfr1[2][2];

  for (int t = 0; t < NT; ++t) {
    // tile-boundary sync: own staging of buf(t) complete (vmcnt), then
    // barrier = everyone done staging t AND done reading t-1.
    asm volatile("s_waitcnt vmcnt(0)" ::: "memory");
    BAR();

    const u16* A = &lds[t & 1][0][0];
    const u16* B = &lds[t & 1][1][0];

    // ---- ALL 24 ds_read_b128, consumption order ----
#pragma unroll
    for (int n = 0; n < 2; ++n)
#pragma unroll
      for (int s = 0; s < 2; ++s)
        bfr0[n][s] = *reinterpret_cast<const bf16x8*>(
            B + (brow + n * 16) * 64 + (fksw ^ (s << 5)));
#pragma unroll
    for (int m = 0; m < 4; ++m)
#pragma unroll
      for (int s = 0; s < 2; ++s)
        af_lo[m][s] = *reinterpret_cast<const bf16x8*>(
            A + (arow + m * 16) * 64 + (fksw ^ (s << 5)));
#pragma unroll
    for (int n = 0; n < 2; ++n)
#pragma unroll
      for (int s = 0; s < 2; ++s)
        bfr1[n][s] = *reinterpret_cast<const bf16x8*>(
            B + (brow + (n + 2) * 16) * 64 + (fksw ^ (s << 5)));
#pragma unroll
    for (int m = 0; m < 4; ++m)
#pragma unroll
      for (int s = 0; s < 2; ++s)
        af_hi[m][s] = *reinterpret_cast<const bf16x8*>(
            A + (arow + (m + 4) * 16) * 64 + (fksw ^ (s << 5)));

    // staging for t+1 (unconditional, clamped — uniform region counts)
    STAGE(t + 1, 0); STAGE(t + 1, 1); STAGE(t + 1, 2); STAGE(t + 1, 3);

    // ---- 64 MFMA in quadrant order ----
    __builtin_amdgcn_s_setprio(1);
#pragma unroll
    for (int m = 0; m < 4; ++m)
#pragma unroll
      for (int n = 0; n < 2; ++n)
#pragma unroll
        for (int s = 0; s < 2; ++s)
          acc[m][n] = __builtin_amdgcn_mfma_f32_16x16x32_bf16(
              af_lo[m][s], bfr0[n][s], acc[m][n], 0, 0, 0);
#pragma unroll
    for (int m = 0; m < 4; ++m)
#pragma unroll
      for (int n = 0; n < 2; ++n)
#pragma unroll
        for (int s = 0; s < 2; ++s)
          acc[m][n + 2] = __builtin_amdgcn_mfma_f32_16x16x32_bf16(
              af_lo[m][s], bfr1[n][s], acc[m][n + 2], 0, 0, 0);
#pragma unroll
    for (int m = 0; m < 4; ++m)
#pragma unroll
      for (int n = 0; n < 2; ++n)
#pragma unroll
        for (int s = 0; s < 2; ++s)
          acc[m + 4][n + 2] = __builtin_amdgcn_mfma_f32_16x16x32_bf16(
              af_hi[m][s], bfr1[n][s], acc[m + 4][n + 2], 0, 0, 0);
#pragma unroll
    for (int m = 0; m < 4; ++m)
#pragma unroll
      for (int n = 0; n < 2; ++n)
#pragma unroll
        for (int s = 0; s < 2; ++s)
          acc[m + 4][n] = __builtin_amdgcn_mfma_f32_16x16x32_bf16(
              af_hi[m][s], bfr0[n][s], acc[m + 4][n], 0, 0, 0);
    __builtin_amdgcn_s_setprio(0);

    // ---- T19 emission script for this region ----
    // masks: MFMA=0x8, VMEM_READ=0x20, DS_READ=0x100
    SGB(0x100, 6, 0);   // bfr0(4) + af_lo[0](2)
    SGB(0x008, 4, 0);   // Q0 m0 (operands: the 6 above)
    SGB(0x100, 6, 0);   // af_lo[1..3]
    SGB(0x008, 12, 0);  // Q0 m1-3
    SGB(0x020, 16, 0);  // 16 global_load_lds (issue early, land by t+1)
    SGB(0x100, 4, 0);   // bfr1
    SGB(0x008, 16, 0);  // Q1
    SGB(0x100, 8, 0);   // af_hi
    SGB(0x008, 16, 0);  // Q2
    SGB(0x008, 16, 0);  // Q3
  }

  // epilogue: C/D layout col = l&15, row = 4*(l>>4)+j
  const int orow = tm * 256 + wr * 128 + ((l >> 4) << 2);
  const int ocol = tn * 256 + wc * 64 + (l & 15);
#pragma unroll
  for (int m = 0; m < 8; ++m)
#pragma unroll
    for (int n = 0; n < 4; ++n) {
      float* cp = C + (size_t)(orow + m * 16) * GN + (ocol + n * 16);
#pragma unroll
      for (int j = 0; j < 4; ++j) cp[(size_t)j * GN] = acc[m][n][j];
    }
}

extern "C" void kernel_launch(void* const* d_in, const int* in_sizes, int n_in,
                              void* d_out, int out_size, void* d_ws, size_t ws_size,
                              hipStream_t stream) {
  const float* x  = (const float*)d_in[0];
  const float* W  = (const float*)d_in[1];
  const float* lA = (const float*)d_in[2];
  const float* lB = (const float*)d_in[3];
  float* out = (float*)d_out;

  u16* weff = (u16*)d_ws;                                        // 32 MiB
  u16* xb = (u16*)((char*)d_ws + (size_t)GN * GK * sizeof(u16)); // 64 MiB

  // fused pre-pass: GN weff-blocks + 8192 cvt-blocks (16 elems/thread)
  prep<<<GN + (GM * GK) / (256 * 16), 256, 0, stream>>>(W, lA, lB, weff, x, xb);
  gemm256<<<(GM / 256) * (GN / 256), 512, 0, stream>>>(xb, weff, out);
}